// Round 2
// baseline (173.063 us; speedup 1.0000x reference)
//
#include <hip/hip_runtime.h>

#define WALK_LEN 40
#define WINDOW   5
#define NPAIRS   370
#define BATCHSZ  512
#define NEGK     5
#define NEG_PER_BATCH (NPAIRS * NEGK)     // 1850
#define NPOS     (BATCHSZ * NPAIRS)       // 189440
#define EMB      128
#define THREADS  512
#define NBLOCKS  (BATCHSZ * 2)            // 2 blocks per batch

struct PairTab { short src[NPAIRS]; short dst[NPAIRS]; };

constexpr PairTab make_pairs() {
    PairTab t{};
    int k = 0;
    for (int i = 0; i < WALK_LEN; ++i) {
        int lo = (i - WINDOW > 0) ? (i - WINDOW) : 0;
        for (int j = lo; j < i; ++j) { t.src[k] = (short)j; t.dst[k] = (short)i; ++k; }
        int hi = (i + 1 + WINDOW < WALK_LEN) ? (i + 1 + WINDOW) : WALK_LEN;
        for (int j = i + 1; j < hi; ++j) { t.src[k] = (short)j; t.dst[k] = (short)i; ++k; }
    }
    return t;
}

__constant__ PairTab g_pairs = make_pairs();

// One block-pair per batch. Stage the batch's 40 node rows + 40 ctx rows in
// LDS (40 KB); positives read LDS only; negatives read LDS (src) + one
// random 512B ctx-row gather (dst).
__global__ __launch_bounds__(THREADS) void deepwalk_blocked(
    const int*   __restrict__ walk,     // [BATCHSZ*WALK_LEN]
    const int*   __restrict__ negdst,   // [BATCHSZ*NEG_PER_BATCH] -> flat walk pos
    const float* __restrict__ nodeE,
    const float* __restrict__ ctxE,
    float*       __restrict__ out)
{
    __shared__ float sN[WALK_LEN][EMB];   // 20 KB
    __shared__ float sC[WALK_LEN][EMB];   // 20 KB
    __shared__ int   swalk[WALK_LEN];
    __shared__ float wsum[THREADS / 64];

    const int b    = blockIdx.x >> 1;
    const int half = blockIdx.x & 1;
    const int tid  = threadIdx.x;

    if (tid < WALK_LEN) swalk[tid] = walk[b * WALK_LEN + tid];
    __syncthreads();

    // stage: 40 rows x 32 float4 per table
    for (int u = tid; u < WALK_LEN * 32; u += THREADS) {
        const int r = u >> 5, l = u & 31;
        const size_t row = (size_t)swalk[r] * EMB;
        ((float4*)sN)[u] = *((const float4*)(nodeE + row) + l);
        ((float4*)sC)[u] = *((const float4*)(ctxE  + row) + l);
    }
    __syncthreads();

    const int lane = tid & 31;
    const int grp  = tid >> 5;            // 0..15
    const int gg   = half * 16 + grp;     // 0..31 across the block pair
    float lsum = 0.f;

    // ---- positives: LDS only ----
    for (int j = gg; j < NPAIRS; j += 32) {
        const float4 a = *((const float4*)sN[g_pairs.src[j]] + lane);
        const float4 c = *((const float4*)sC[g_pairs.dst[j]] + lane);
        float d = a.x * c.x + a.y * c.y + a.z * c.z + a.w * c.w;
        #pragma unroll
        for (int m = 1; m < 32; m <<= 1) d += __shfl_xor(d, m);
        if (lane == 0) {
            const float s = fminf(6.f, fmaxf(-6.f, d));
            lsum += log1pf(__expf(-s));
        }
    }

    // ---- negatives: LDS src + global ctx-row gather, 1-deep index prefetch ----
    const int* nb = negdst + b * NEG_PER_BATCH;
    int t = gg;
    int drow = (t < NEG_PER_BATCH) ? walk[nb[t]] : 0;
    for (; t < NEG_PER_BATCH; t += 32) {
        const int tn = t + 32;
        const int drow_next = (tn < NEG_PER_BATCH) ? walk[nb[tn]] : 0;

        const int p = t / NEGK;                              // parent positive pair
        const float4 a = *((const float4*)sN[g_pairs.dst[p]] + lane);
        const float4 c = *((const float4*)(ctxE + (size_t)drow * EMB) + lane);
        float d = a.x * c.x + a.y * c.y + a.z * c.z + a.w * c.w;
        #pragma unroll
        for (int m = 1; m < 32; m <<= 1) d += __shfl_xor(d, m);
        if (lane == 0) {
            const float s = fminf(6.f, fmaxf(-6.f, d));
            lsum += log1pf(__expf(s));
        }
        drow = drow_next;
    }

    // ---- block reduce ----
    lsum += __shfl_xor(lsum, 32);                 // merge the two 32-lane halves
    if ((tid & 63) == 0) wsum[tid >> 6] = lsum;
    __syncthreads();
    if (tid == 0) {
        float tot = 0.f;
        #pragma unroll
        for (int w = 0; w < THREADS / 64; ++w) tot += wsum[w];
        atomicAdd(out, tot * (1.0f / (float)NPOS));
    }
}

extern "C" void kernel_launch(void* const* d_in, const int* in_sizes, int n_in,
                              void* d_out, int out_size, void* d_ws, size_t ws_size,
                              hipStream_t stream) {
    const int*   walk   = (const int*)d_in[0];
    const int*   negdst = (const int*)d_in[1];
    const float* nodeE  = (const float*)d_in[2];
    const float* ctxE   = (const float*)d_in[3];
    float*       out    = (float*)d_out;

    hipMemsetAsync(out, 0, sizeof(float), stream);
    deepwalk_blocked<<<NBLOCKS, THREADS, 0, stream>>>(walk, negdst, nodeE, ctxE, out);
}

// Round 4
// 68.211 us; speedup vs baseline: 2.5371x; 2.5371x over previous
//
#include <hip/hip_runtime.h>

#define WALK_LEN 40
#define WINDOW   5
#define NPAIRS   370
#define BATCHSZ  512
#define NEGK     5
#define NPOS     (BATCHSZ * NPAIRS)        // 189440
#define EMB      128
#define THREADS  256
#define GROUPS_PER_BLOCK (THREADS / 8)     // 32 groups of 8 lanes
#define NBLOCKS  (NPOS / GROUPS_PER_BLOCK) // 5920 (exact)

struct PairTab { short src[NPAIRS]; short dst[NPAIRS]; };

constexpr PairTab make_pairs() {
    PairTab t{};
    int k = 0;
    for (int i = 0; i < WALK_LEN; ++i) {
        int lo = (i - WINDOW > 0) ? (i - WINDOW) : 0;
        for (int j = lo; j < i; ++j) { t.src[k] = (short)j; t.dst[k] = (short)i; ++k; }
        int hi = (i + 1 + WINDOW < WALK_LEN) ? (i + 1 + WINDOW) : WALK_LEN;
        for (int j = i + 1; j < hi; ++j) { t.src[k] = (short)j; t.dst[k] = (short)i; ++k; }
    }
    return t;
}

__constant__ PairTab g_pairs = make_pairs();

__device__ __forceinline__ float dot4(float4 a, float4 b) {
    return a.x * b.x + a.y * b.y + a.z * b.z + a.w * b.w;
}

// lane l of an 8-lane group owns float4 indices l, l+8, l+16, l+24 of a row
// (each load instruction = one contiguous 128B cache line per group).
#define LOAD_ROW(v0, v1, v2, v3, baseptr)            \
    do {                                             \
        const float4* _r = (baseptr);                \
        v0 = _r[lane8];      v1 = _r[lane8 + 8];     \
        v2 = _r[lane8 + 16]; v3 = _r[lane8 + 24];    \
    } while (0)

#define DOT_REDUCE(d, a0, a1, a2, a3, c0, c1, c2, c3)                 \
    do {                                                              \
        d = dot4(a0, c0) + dot4(a1, c1) + dot4(a2, c2) + dot4(a3, c3);\
        d += __shfl_xor(d, 1);                                        \
        d += __shfl_xor(d, 2);                                        \
        d += __shfl_xor(d, 4);                                        \
    } while (0)

// One 8-lane group per positive pair p: computes the positive term and the
// 5 negative terms (which share node[walk[dst_j]] as their src row).
__global__ __launch_bounds__(THREADS) void dw_score(
    const int*   __restrict__ walk,     // [BATCHSZ*WALK_LEN]
    const int*   __restrict__ negdst,   // [NPOS*NEGK] -> flat-walk positions
    const float* __restrict__ nodeE,
    const float* __restrict__ ctxE,
    float*       __restrict__ partial)  // [NBLOCKS]
{
    const int tid   = threadIdx.x;
    const int lane8 = tid & 7;
    const int p     = (blockIdx.x * THREADS + tid) >> 3;   // 0..NPOS-1

    const int b  = p / NPAIRS;
    const int j  = p - b * NPAIRS;
    const int sj = g_pairs.src[j];
    const int dj = g_pairs.dst[j];
    const int srow = walk[b * WALK_LEN + sj];
    const int drow = walk[b * WALK_LEN + dj];

    // negative dst rows: issue the 5 independent 2-deep index chains up front
    const int* nb = negdst + p * NEGK;
    int nrow[NEGK];
    #pragma unroll
    for (int k = 0; k < NEGK; ++k) nrow[k] = walk[nb[k]];

    float acc = 0.0f;

    // ---- positive: dot(node[srow], ctx[drow]) ----
    {
        float4 a0, a1, a2, a3, c0, c1, c2, c3;
        LOAD_ROW(a0, a1, a2, a3, (const float4*)(nodeE + (size_t)srow * EMB));
        LOAD_ROW(c0, c1, c2, c3, (const float4*)(ctxE  + (size_t)drow * EMB));
        float d;
        DOT_REDUCE(d, a0, a1, a2, a3, c0, c1, c2, c3);
        const float s = fminf(6.f, fmaxf(-6.f, d));
        acc += log1pf(__expf(-s));
    }

    // ---- negatives: src row node[drow] shared, dst rows double-buffered ----
    {
        float4 n0, n1, n2, n3;
        LOAD_ROW(n0, n1, n2, n3, (const float4*)(nodeE + (size_t)drow * EMB));

        float4 x0, x1, x2, x3;   // buffer A
        float4 y0, y1, y2, y3;   // buffer B
        LOAD_ROW(x0, x1, x2, x3, (const float4*)(ctxE + (size_t)nrow[0] * EMB));

        float d;
        // k=0: use A, prefetch k=1 into B
        LOAD_ROW(y0, y1, y2, y3, (const float4*)(ctxE + (size_t)nrow[1] * EMB));
        DOT_REDUCE(d, n0, n1, n2, n3, x0, x1, x2, x3);
        { const float s = fminf(6.f, fmaxf(-6.f, d)); acc += log1pf(__expf(s)); }
        // k=1: use B, prefetch k=2 into A
        LOAD_ROW(x0, x1, x2, x3, (const float4*)(ctxE + (size_t)nrow[2] * EMB));
        DOT_REDUCE(d, n0, n1, n2, n3, y0, y1, y2, y3);
        { const float s = fminf(6.f, fmaxf(-6.f, d)); acc += log1pf(__expf(s)); }
        // k=2: use A, prefetch k=3 into B
        LOAD_ROW(y0, y1, y2, y3, (const float4*)(ctxE + (size_t)nrow[3] * EMB));
        DOT_REDUCE(d, n0, n1, n2, n3, x0, x1, x2, x3);
        { const float s = fminf(6.f, fmaxf(-6.f, d)); acc += log1pf(__expf(s)); }
        // k=3: use B, prefetch k=4 into A
        LOAD_ROW(x0, x1, x2, x3, (const float4*)(ctxE + (size_t)nrow[4] * EMB));
        DOT_REDUCE(d, n0, n1, n2, n3, y0, y1, y2, y3);
        { const float s = fminf(6.f, fmaxf(-6.f, d)); acc += log1pf(__expf(s)); }
        // k=4: use A
        DOT_REDUCE(d, n0, n1, n2, n3, x0, x1, x2, x3);
        { const float s = fminf(6.f, fmaxf(-6.f, d)); acc += log1pf(__expf(s)); }
    }

    // acc_g is replicated on the 8 lanes of group g. The xor-8/16/32 tree
    // combines one representative lane from each of the 8 groups in the wave:
    // every lane ends holding sum over the wave's 8 groups, each counted ONCE.
    acc += __shfl_xor(acc, 8);
    acc += __shfl_xor(acc, 16);
    acc += __shfl_xor(acc, 32);

    __shared__ float wsum[THREADS / 64];
    if ((tid & 63) == 0) wsum[tid >> 6] = acc;
    __syncthreads();
    if (tid == 0) {
        float tot = 0.f;
        #pragma unroll
        for (int w = 0; w < THREADS / 64; ++w) tot += wsum[w];
        partial[blockIdx.x] = tot;
    }
}

__global__ __launch_bounds__(256) void dw_reduce(
    const float* __restrict__ partial, float* __restrict__ out)
{
    const int tid = threadIdx.x;
    float s = 0.f;
    for (int i = tid; i < NBLOCKS; i += 256) s += partial[i];
    #pragma unroll
    for (int m = 1; m < 64; m <<= 1) s += __shfl_xor(s, m);
    __shared__ float wsum[4];
    if ((tid & 63) == 0) wsum[tid >> 6] = s;
    __syncthreads();
    if (tid == 0)
        out[0] = (wsum[0] + wsum[1] + wsum[2] + wsum[3]) * (1.0f / (float)NPOS);
}

extern "C" void kernel_launch(void* const* d_in, const int* in_sizes, int n_in,
                              void* d_out, int out_size, void* d_ws, size_t ws_size,
                              hipStream_t stream) {
    const int*   walk   = (const int*)d_in[0];
    const int*   negdst = (const int*)d_in[1];
    const float* nodeE  = (const float*)d_in[2];
    const float* ctxE   = (const float*)d_in[3];
    float*       out    = (float*)d_out;
    float*       part   = (float*)d_ws;

    dw_score<<<NBLOCKS, THREADS, 0, stream>>>(walk, negdst, nodeE, ctxE, part);
    dw_reduce<<<1, 256, 0, stream>>>(part, out);
}

// Round 5
// 63.242 us; speedup vs baseline: 2.7365x; 1.0786x over previous
//
#include <hip/hip_runtime.h>

#define WALK_LEN 40
#define WINDOW   5
#define NPAIRS   370
#define BATCHSZ  512
#define NEGK     5
#define NPOS     (BATCHSZ * NPAIRS)        // 189440
#define EMB      128
#define THREADS  512
#define GROUPS   (THREADS / 8)             // 64 8-lane groups
#define HALFP    185                       // pairs per block (2 blocks/batch)
#define NBLOCKS  (BATCHSZ * 2)             // 1024

struct PairTab { short src[NPAIRS]; short dst[NPAIRS]; };

constexpr PairTab make_pairs() {
    PairTab t{};
    int k = 0;
    for (int i = 0; i < WALK_LEN; ++i) {
        int lo = (i - WINDOW > 0) ? (i - WINDOW) : 0;
        for (int j = lo; j < i; ++j) { t.src[k] = (short)j; t.dst[k] = (short)i; ++k; }
        int hi = (i + 1 + WINDOW < WALK_LEN) ? (i + 1 + WINDOW) : WALK_LEN;
        for (int j = i + 1; j < hi; ++j) { t.src[k] = (short)j; t.dst[k] = (short)i; ++k; }
    }
    return t;
}

__constant__ PairTab g_pairs = make_pairs();

__device__ __forceinline__ float dot4(float4 a, float4 b) {
    return a.x * b.x + a.y * b.y + a.z * b.z + a.w * b.w;
}

// lane l of an 8-lane group owns float4 indices l, l+8, l+16, l+24 of a row.
#define LOAD_ROW(v0, v1, v2, v3, baseptr)            \
    do {                                             \
        const float4* _r = (baseptr);                \
        v0 = _r[lane8];      v1 = _r[lane8 + 8];     \
        v2 = _r[lane8 + 16]; v3 = _r[lane8 + 24];    \
    } while (0)

#define DOT_REDUCE(d, a0, a1, a2, a3, c0, c1, c2, c3)                 \
    do {                                                              \
        d = dot4(a0, c0) + dot4(a1, c1) + dot4(a2, c2) + dot4(a3, c3);\
        d += __shfl_xor(d, 1);                                        \
        d += __shfl_xor(d, 2);                                        \
        d += __shfl_xor(d, 4);                                        \
    } while (0)

// One block = half a batch (185 pairs). Batch's 40 node + 40 ctx rows staged
// in LDS; positives and neg-src read LDS; only neg-dst ctx rows are gathered
// from global (L3), double-buffered 2-deep as in R4.
__global__ __launch_bounds__(THREADS) void dw_score(
    const int*   __restrict__ walk,     // [BATCHSZ*WALK_LEN]
    const int*   __restrict__ negdst,   // [NPOS*NEGK] -> flat-walk positions
    const float* __restrict__ nodeE,
    const float* __restrict__ ctxE,
    float*       __restrict__ partial)  // [NBLOCKS]
{
    __shared__ float sN[WALK_LEN][EMB];   // 20 KB
    __shared__ float sC[WALK_LEN][EMB];   // 20 KB
    __shared__ int   swalk[WALK_LEN];
    __shared__ float wsum[THREADS / 64];

    const int b    = blockIdx.x >> 1;
    const int half = blockIdx.x & 1;
    const int tid  = threadIdx.x;

    if (tid < WALK_LEN) swalk[tid] = walk[b * WALK_LEN + tid];
    __syncthreads();

    for (int u = tid; u < WALK_LEN * 32; u += THREADS) {
        const int r = u >> 5, l = u & 31;
        const size_t row = (size_t)swalk[r] * EMB;
        ((float4*)sN)[u] = *((const float4*)(nodeE + row) + l);
        ((float4*)sC)[u] = *((const float4*)(ctxE  + row) + l);
    }
    __syncthreads();

    const int lane8 = tid & 7;
    const int grp   = tid >> 3;           // 0..63
    const int jbase = half * HALFP;
    float acc = 0.0f;

    #pragma unroll 1
    for (int it = 0; it < 3; ++it) {
        const int jj = it * GROUPS + grp;           // 0..191
        if (jj < HALFP) {
            const int j = jbase + jj;               // 0..369
            const int p = b * NPAIRS + j;
            const int sj = g_pairs.src[j];
            const int dj = g_pairs.dst[j];

            // neg-dst rows: 5 independent 2-deep index chains, issued up front
            const int* nb = negdst + p * NEGK;
            int nrow[NEGK];
            #pragma unroll
            for (int k = 0; k < NEGK; ++k) nrow[k] = walk[nb[k]];

            // ---- positive: LDS only ----
            {
                float4 a0, a1, a2, a3, c0, c1, c2, c3;
                LOAD_ROW(a0, a1, a2, a3, (const float4*)sN[sj]);
                LOAD_ROW(c0, c1, c2, c3, (const float4*)sC[dj]);
                float d;
                DOT_REDUCE(d, a0, a1, a2, a3, c0, c1, c2, c3);
                const float s = fminf(6.f, fmaxf(-6.f, d));
                acc += log1pf(__expf(-s));
            }

            // ---- negatives: src row from LDS, dst rows double-buffered global ----
            {
                float4 n0, n1, n2, n3;
                LOAD_ROW(n0, n1, n2, n3, (const float4*)sN[dj]);

                float4 x0, x1, x2, x3;   // buffer A
                float4 y0, y1, y2, y3;   // buffer B
                LOAD_ROW(x0, x1, x2, x3, (const float4*)(ctxE + (size_t)nrow[0] * EMB));

                float d;
                // k=0: use A, prefetch k=1 into B
                LOAD_ROW(y0, y1, y2, y3, (const float4*)(ctxE + (size_t)nrow[1] * EMB));
                DOT_REDUCE(d, n0, n1, n2, n3, x0, x1, x2, x3);
                { const float s = fminf(6.f, fmaxf(-6.f, d)); acc += log1pf(__expf(s)); }
                // k=1: use B, prefetch k=2 into A
                LOAD_ROW(x0, x1, x2, x3, (const float4*)(ctxE + (size_t)nrow[2] * EMB));
                DOT_REDUCE(d, n0, n1, n2, n3, y0, y1, y2, y3);
                { const float s = fminf(6.f, fmaxf(-6.f, d)); acc += log1pf(__expf(s)); }
                // k=2: use A, prefetch k=3 into B
                LOAD_ROW(y0, y1, y2, y3, (const float4*)(ctxE + (size_t)nrow[3] * EMB));
                DOT_REDUCE(d, n0, n1, n2, n3, x0, x1, x2, x3);
                { const float s = fminf(6.f, fmaxf(-6.f, d)); acc += log1pf(__expf(s)); }
                // k=3: use B, prefetch k=4 into A
                LOAD_ROW(x0, x1, x2, x3, (const float4*)(ctxE + (size_t)nrow[4] * EMB));
                DOT_REDUCE(d, n0, n1, n2, n3, y0, y1, y2, y3);
                { const float s = fminf(6.f, fmaxf(-6.f, d)); acc += log1pf(__expf(s)); }
                // k=4: use A
                DOT_REDUCE(d, n0, n1, n2, n3, x0, x1, x2, x3);
                { const float s = fminf(6.f, fmaxf(-6.f, d)); acc += log1pf(__expf(s)); }
            }
        }
    }

    // acc_g replicated on each group's 8 lanes; xor-8/16/32 combines one
    // representative per group -> wave sum (each group counted once).
    acc += __shfl_xor(acc, 8);
    acc += __shfl_xor(acc, 16);
    acc += __shfl_xor(acc, 32);

    if ((tid & 63) == 0) wsum[tid >> 6] = acc;
    __syncthreads();
    if (tid == 0) {
        float tot = 0.f;
        #pragma unroll
        for (int w = 0; w < THREADS / 64; ++w) tot += wsum[w];
        partial[blockIdx.x] = tot;
    }
}

__global__ __launch_bounds__(256) void dw_reduce(
    const float* __restrict__ partial, float* __restrict__ out)
{
    const int tid = threadIdx.x;
    float s = 0.f;
    for (int i = tid; i < NBLOCKS; i += 256) s += partial[i];
    #pragma unroll
    for (int m = 1; m < 64; m <<= 1) s += __shfl_xor(s, m);
    __shared__ float wsum[4];
    if ((tid & 63) == 0) wsum[tid >> 6] = s;
    __syncthreads();
    if (tid == 0)
        out[0] = (wsum[0] + wsum[1] + wsum[2] + wsum[3]) * (1.0f / (float)NPOS);
}

extern "C" void kernel_launch(void* const* d_in, const int* in_sizes, int n_in,
                              void* d_out, int out_size, void* d_ws, size_t ws_size,
                              hipStream_t stream) {
    const int*   walk   = (const int*)d_in[0];
    const int*   negdst = (const int*)d_in[1];
    const float* nodeE  = (const float*)d_in[2];
    const float* ctxE   = (const float*)d_in[3];
    float*       out    = (float*)d_out;
    float*       part   = (float*)d_ws;

    dw_score<<<NBLOCKS, THREADS, 0, stream>>>(walk, negdst, nodeE, ctxE, part);
    dw_reduce<<<1, 256, 0, stream>>>(part, out);
}

// Round 6
// 58.405 us; speedup vs baseline: 2.9631x; 1.0828x over previous
//
#include <hip/hip_runtime.h>

#define WALK_LEN 40
#define WINDOW   5
#define NPAIRS   370
#define BATCHSZ  512
#define NEGK     5
#define NPOS     (BATCHSZ * NPAIRS)        // 189440
#define EMB      128
#define NQ       (BATCHSZ * WALK_LEN)      // 20480 flat-walk rows
#define THREADS  512
#define GROUPS   (THREADS / 8)             // 64 8-lane groups
#define HALFP    185                       // pairs per block (2 blocks/batch)
#define NBLOCKS  (BATCHSZ * 2)             // 1024

struct PairTab { short src[NPAIRS]; short dst[NPAIRS]; };

constexpr PairTab make_pairs() {
    PairTab t{};
    int k = 0;
    for (int i = 0; i < WALK_LEN; ++i) {
        int lo = (i - WINDOW > 0) ? (i - WINDOW) : 0;
        for (int j = lo; j < i; ++j) { t.src[k] = (short)j; t.dst[k] = (short)i; ++k; }
        int hi = (i + 1 + WINDOW < WALK_LEN) ? (i + 1 + WINDOW) : WALK_LEN;
        for (int j = i + 1; j < hi; ++j) { t.src[k] = (short)j; t.dst[k] = (short)i; ++k; }
    }
    return t;
}

__constant__ PairTab g_pairs = make_pairs();

__device__ __forceinline__ unsigned short bf16rn(float f) {
    unsigned u = __float_as_uint(f);
    u += 0x7fffu + ((u >> 16) & 1u);
    return (unsigned short)(u >> 16);
}

// dot of 8 bf16 pairs packed as uint4 (2 bf16 per uint), accumulated in f32
__device__ __forceinline__ float dot_u4(uint4 a, uint4 c) {
    float s = 0.f;
    #pragma unroll
    for (int i = 0; i < 4; ++i) {
        const unsigned av = (&a.x)[i], cv = (&c.x)[i];
        const float a0 = __uint_as_float(av << 16);
        const float a1 = __uint_as_float(av & 0xffff0000u);
        const float c0 = __uint_as_float(cv << 16);
        const float c1 = __uint_as_float(cv & 0xffff0000u);
        s = fmaf(a0, c0, s);
        s = fmaf(a1, c1, s);
    }
    return s;
}

// ---- phase 1: gather the 20480 flat-walk rows of each table into dense bf16 ----
// thread = one float4 chunk; first NQ*32 threads do node, next NQ*32 do ctx.
__global__ __launch_bounds__(256) void dw_gather(
    const int*   __restrict__ walk,
    const float* __restrict__ nodeE,
    const float* __restrict__ ctxE,
    unsigned short* __restrict__ dN,
    unsigned short* __restrict__ dC)
{
    int idx = blockIdx.x * 256 + threadIdx.x;      // 0 .. 2*NQ*32-1
    const int is_ctx = (idx >= NQ * 32);
    if (is_ctx) idx -= NQ * 32;
    const int q = idx >> 5, c = idx & 31;
    const int row = walk[q];
    const float* src = (is_ctx ? ctxE : nodeE) + (size_t)row * EMB;
    const float4 v = *((const float4*)src + c);
    ushort4 o;
    o.x = bf16rn(v.x); o.y = bf16rn(v.y); o.z = bf16rn(v.z); o.w = bf16rn(v.w);
    unsigned short* dst = (is_ctx ? dC : dN) + (size_t)q * EMB;
    *((ushort4*)dst + c) = o;
}

// ---- phase 2: one block = half a batch (185 pairs) ----
// Batch's 40 node + 40 ctx bf16 rows staged in LDS (20 KB, from CONTIGUOUS
// dense memory). Positives + neg-src read LDS; neg-dst rows (256 B each) are
// gathered from the dense bf16 ctx buffer, all 5 issued up-front.
__global__ __launch_bounds__(THREADS) void dw_score(
    const int* __restrict__ negdst,                 // [NPOS*NEGK] -> flat pos (= dense row)
    const unsigned short* __restrict__ dN,
    const unsigned short* __restrict__ dC,
    float* __restrict__ partial)                    // [NBLOCKS]
{
    __shared__ unsigned int sN[WALK_LEN * 64];      // 10 KB (row = 64 uints = 256 B)
    __shared__ unsigned int sC[WALK_LEN * 64];      // 10 KB
    __shared__ float wsum[THREADS / 64];

    const int b    = blockIdx.x >> 1;
    const int half = blockIdx.x & 1;
    const int tid  = threadIdx.x;

    // stage: 640 uint4 per table, contiguous
    {
        const uint4* srcN = (const uint4*)(dN + (size_t)b * WALK_LEN * EMB);
        const uint4* srcC = (const uint4*)(dC + (size_t)b * WALK_LEN * EMB);
        for (int u = tid; u < WALK_LEN * 16; u += THREADS) {
            ((uint4*)sN)[u] = srcN[u];
            ((uint4*)sC)[u] = srcC[u];
        }
    }
    __syncthreads();

    const int lane8 = tid & 7;
    const int grp   = tid >> 3;           // 0..63
    const int jbase = half * HALFP;
    float acc = 0.0f;

    #pragma unroll 1
    for (int it = 0; it < 3; ++it) {
        const int jj = it * GROUPS + grp;           // 0..191
        if (jj < HALFP) {
            const int j = jbase + jj;
            const int p = b * NPAIRS + j;
            const int sj = g_pairs.src[j];
            const int dj = g_pairs.dst[j];

            const int* nb = negdst + p * NEGK;
            const int q0 = nb[0], q1 = nb[1], q2 = nb[2], q3 = nb[3], q4 = nb[4];

            // issue all 5 neg-dst row gathers (10 loads, 2 per row) up front
            const uint4* g0 = (const uint4*)(dC + (size_t)q0 * EMB);
            const uint4* g1 = (const uint4*)(dC + (size_t)q1 * EMB);
            const uint4* g2 = (const uint4*)(dC + (size_t)q2 * EMB);
            const uint4* g3 = (const uint4*)(dC + (size_t)q3 * EMB);
            const uint4* g4 = (const uint4*)(dC + (size_t)q4 * EMB);
            const uint4 x00 = g0[lane8], x01 = g0[lane8 + 8];
            const uint4 x10 = g1[lane8], x11 = g1[lane8 + 8];
            const uint4 x20 = g2[lane8], x21 = g2[lane8 + 8];
            const uint4 x30 = g3[lane8], x31 = g3[lane8 + 8];
            const uint4 x40 = g4[lane8], x41 = g4[lane8 + 8];

            // LDS fragments
            const uint4* rN = (const uint4*)(sN + sj * 64);
            const uint4* rC = (const uint4*)(sC + dj * 64);
            const uint4* rS = (const uint4*)(sN + dj * 64);   // neg src row
            const uint4 a0 = rN[lane8], a1 = rN[lane8 + 8];
            const uint4 c0 = rC[lane8], c1 = rC[lane8 + 8];
            const uint4 n0 = rS[lane8], n1 = rS[lane8 + 8];

            // ---- positive (LDS only, overlaps gather latency) ----
            {
                float d = dot_u4(a0, c0) + dot_u4(a1, c1);
                d += __shfl_xor(d, 1); d += __shfl_xor(d, 2); d += __shfl_xor(d, 4);
                const float s = fminf(6.f, fmaxf(-6.f, d));
                acc += log1pf(__expf(-s));
            }

            // ---- negatives ----
            #define NEG_TERM(xa, xb)                                              \
            do {                                                                  \
                float d = dot_u4(n0, xa) + dot_u4(n1, xb);                        \
                d += __shfl_xor(d, 1); d += __shfl_xor(d, 2); d += __shfl_xor(d, 4);\
                const float s = fminf(6.f, fmaxf(-6.f, d));                       \
                acc += log1pf(__expf(s));                                         \
            } while (0)
            NEG_TERM(x00, x01);
            NEG_TERM(x10, x11);
            NEG_TERM(x20, x21);
            NEG_TERM(x30, x31);
            NEG_TERM(x40, x41);
            #undef NEG_TERM
        }
    }

    // group sums -> wave sum (each group counted once)
    acc += __shfl_xor(acc, 8);
    acc += __shfl_xor(acc, 16);
    acc += __shfl_xor(acc, 32);

    if ((tid & 63) == 0) wsum[tid >> 6] = acc;
    __syncthreads();
    if (tid == 0) {
        float tot = 0.f;
        #pragma unroll
        for (int w = 0; w < THREADS / 64; ++w) tot += wsum[w];
        partial[blockIdx.x] = tot;
    }
}

__global__ __launch_bounds__(256) void dw_reduce(
    const float* __restrict__ partial, float* __restrict__ out)
{
    const int tid = threadIdx.x;
    float s = 0.f;
    for (int i = tid; i < NBLOCKS; i += 256) s += partial[i];
    #pragma unroll
    for (int m = 1; m < 64; m <<= 1) s += __shfl_xor(s, m);
    __shared__ float wsum[4];
    if ((tid & 63) == 0) wsum[tid >> 6] = s;
    __syncthreads();
    if (tid == 0)
        out[0] = (wsum[0] + wsum[1] + wsum[2] + wsum[3]) * (1.0f / (float)NPOS);
}

extern "C" void kernel_launch(void* const* d_in, const int* in_sizes, int n_in,
                              void* d_out, int out_size, void* d_ws, size_t ws_size,
                              hipStream_t stream) {
    const int*   walk   = (const int*)d_in[0];
    const int*   negdst = (const int*)d_in[1];
    const float* nodeE  = (const float*)d_in[2];
    const float* ctxE   = (const float*)d_in[3];
    float*       out    = (float*)d_out;

    unsigned short* dN = (unsigned short*)d_ws;
    unsigned short* dC = dN + (size_t)NQ * EMB;
    float* part = (float*)((char*)d_ws + (16u << 20));   // 16 MB offset

    dw_gather<<<(2 * NQ * 32) / 256, 256, 0, stream>>>(walk, nodeE, ctxE, dN, dC);
    dw_score<<<NBLOCKS, THREADS, 0, stream>>>(negdst, dN, dC, part);
    dw_reduce<<<1, 256, 0, stream>>>(part, out);
}